// Round 1
// baseline (89.107 us; speedup 1.0000x reference)
//
#include <hip/hip_runtime.h>

// SystemIDModel: y[k] = poly8(x2[k]) - x1[k] - R0*u[k]
//   x1[k] = A00*x1[k-1] + B0*u[k-1]   (x1[0]=0)      A00 = exp(-dt/(Rp*Cp)), B0 = Rp*(1-A00)
//   x2[k] = x2[k-1] + B1*u[k-1]       (x2[0]=1)      B1 = -eta*dt/Qn = -1/5400
// Parallelized as 3-pass chunked scan; fp64 internally (memory-bound, fp64 free).

constexpr int    BLOCK = 256;
constexpr int    TPER  = 16;
constexpr int    CHUNK = BLOCK * TPER;        // 4096
constexpr int    NTOT  = 4194304;
constexpr int    NB    = NTOT / CHUNK;        // 1024

// ---------------- Kernel 1: per-chunk aggregates ----------------
__global__ __launch_bounds__(BLOCK) void k1_agg(
    const float* __restrict__ u,
    const float* __restrict__ Rp_p, const float* __restrict__ Cp_p,
    double* __restrict__ wsS, double* __restrict__ wsP)
{
    __shared__ double sS[BLOCK];
    __shared__ double sPm[BLOCK];
    const int b = blockIdx.x, t = threadIdx.x;
    const double invRC = 1.0 / ((double)Rp_p[0] * (double)Cp_p[0]);
    const double A00 = exp(-invRC);

    const float4* up = (const float4*)(u + (size_t)b * CHUNK + (size_t)t * TPER);
    float4 v[4];
    v[0] = up[0]; v[1] = up[1]; v[2] = up[2]; v[3] = up[3];
    const float* uu = (const float*)v;

    double s = 0.0, p = 0.0;
#pragma unroll
    for (int i = 0; i < TPER; ++i) { s = A00 * s + (double)uu[i]; p += (double)uu[i]; }
    sS[t] = s; sPm[t] = p;
    __syncthreads();

    // ordered tree reduce: combine(L,R): S = S_L * A00^{len_R} + S_R
    double f = exp(-(double)TPER * invRC);    // A00^16
    for (int stride = 1; stride < BLOCK; stride <<= 1) {
        if ((t & (2 * stride - 1)) == 0) {
            sS[t]  = sS[t] * f + sS[t + stride];
            sPm[t] = sPm[t] + sPm[t + stride];
        }
        f *= f;
        __syncthreads();
    }
    if (t == 0) { wsS[b] = sS[0]; wsP[b] = sPm[0]; }
}

// ---------------- Kernel 2: exclusive scan of chunk aggregates ----------------
__global__ __launch_bounds__(NB) void k2_scan(
    const float* __restrict__ Rp_p, const float* __restrict__ Cp_p,
    const double* __restrict__ wsS, const double* __restrict__ wsP,
    double* __restrict__ wsWc, double* __restrict__ wsPc)
{
    __shared__ double sW[2][NB];   // 16 KB
    __shared__ double sP[2][NB];   // 16 KB
    const int t = threadIdx.x;
    const double invRC = 1.0 / ((double)Rp_p[0] * (double)Cp_p[0]);

    sW[0][t] = wsS[t]; sP[0][t] = wsP[t];
    __syncthreads();

    double f = exp(-(double)CHUNK * invRC);   // A00^CHUNK (underflow->0 is correct)
    int cur = 0;
    for (int d = 1; d < NB; d <<= 1) {
        const int nxt = cur ^ 1;
        double w = sW[cur][t], p = sP[cur][t];
        if (t >= d) { w = sW[cur][t - d] * f + w; p = sP[cur][t - d] + p; }
        sW[nxt][t] = w; sP[nxt][t] = p;
        cur = nxt; f *= f;
        __syncthreads();
    }
    wsWc[t] = (t == 0) ? 0.0 : sW[cur][t - 1];
    wsPc[t] = (t == 0) ? 0.0 : sP[cur][t - 1];
}

// ---------------- Kernel 3: rescan + emit ----------------
__global__ __launch_bounds__(BLOCK) void k3_emit(
    const float* __restrict__ u,
    const float* __restrict__ Rp_p, const float* __restrict__ Cp_p,
    const float* __restrict__ R0_p, const float* __restrict__ ac,
    const double* __restrict__ wsWc, const double* __restrict__ wsPc,
    float* __restrict__ out)
{
    __shared__ double sS[2][BLOCK];
    __shared__ double sP[2][BLOCK];
    const int b = blockIdx.x, t = threadIdx.x;
    const double Rp = (double)Rp_p[0], Cp = (double)Cp_p[0];
    const double invRC = 1.0 / (Rp * Cp);
    const double A00 = exp(-invRC);
    const double B0  = Rp * (1.0 - A00);
    const double B1  = -1.0 / 5400.0;                // -eta*dt/(1.5*3600)
    const double R0  = (double)R0_p[0];
    double a[9];
#pragma unroll
    for (int i = 0; i < 9; ++i) a[i] = (double)ac[i];

    const size_t base = (size_t)b * CHUNK + (size_t)t * TPER;
    const float4* up = (const float4*)(u + base);
    float4 v[4];
    v[0] = up[0]; v[1] = up[1]; v[2] = up[2]; v[3] = up[3];
    const float* uu = (const float*)v;

    double s = 0.0, p = 0.0;
#pragma unroll
    for (int i = 0; i < TPER; ++i) { s = A00 * s + (double)uu[i]; p += (double)uu[i]; }
    sS[0][t] = s; sP[0][t] = p;
    __syncthreads();

    // inclusive Hillis-Steele across thread aggregates
    double f = exp(-(double)TPER * invRC);
    int cur = 0;
    for (int d = 1; d < BLOCK; d <<= 1) {
        const int nxt = cur ^ 1;
        double w = sS[cur][t], q = sP[cur][t];
        if (t >= d) { w = sS[cur][t - d] * f + w; q = sP[cur][t - d] + q; }
        sS[nxt][t] = w; sP[nxt][t] = q;
        cur = nxt; f *= f;
        __syncthreads();
    }
    const double exW = (t == 0) ? 0.0 : sS[cur][t - 1];
    const double exP = (t == 0) ? 0.0 : sP[cur][t - 1];
    const double W0 = wsWc[b], P0 = wsPc[b];

    double Wcur = exp(-(double)(TPER * t) * invRC) * W0 + exW;  // W at element base
    double Pcur = P0 + exP;

    float4 o[4];
    float* oy = (float*)o;
#pragma unroll
    for (int i = 0; i < TPER; ++i) {
        const double x2 = 1.0 + B1 * Pcur;   // INITIAL_X2 = 1
        const double x1 = B0 * Wcur;
        double poly = a[8];
#pragma unroll
        for (int j = 7; j >= 0; --j) poly = poly * x2 + a[j];
        oy[i] = (float)(poly - x1 - R0 * (double)uu[i]);
        Wcur = A00 * Wcur + (double)uu[i];   // state AFTER consuming u[k]
        Pcur += (double)uu[i];
    }
    float4* op = (float4*)(out + base);
    op[0] = o[0]; op[1] = o[1]; op[2] = o[2]; op[3] = o[3];
}

extern "C" void kernel_launch(void* const* d_in, const int* in_sizes, int n_in,
                              void* d_out, int out_size, void* d_ws, size_t ws_size,
                              hipStream_t stream) {
    const float* u    = (const float*)d_in[0];
    const float* Rp_p = (const float*)d_in[1];
    const float* Cp_p = (const float*)d_in[2];
    const float* R0_p = (const float*)d_in[3];
    const float* ac   = (const float*)d_in[4];
    float* out = (float*)d_out;

    double* ws   = (double*)d_ws;
    double* wsS  = ws;            // [NB] chunk weighted sums
    double* wsP  = ws + NB;       // [NB] chunk plain sums
    double* wsWc = ws + 2 * NB;   // [NB] exclusive carries (weighted)
    double* wsPc = ws + 3 * NB;   // [NB] exclusive carries (plain)

    k1_agg <<<NB, BLOCK, 0, stream>>>(u, Rp_p, Cp_p, wsS, wsP);
    k2_scan<<<1,  NB,    0, stream>>>(Rp_p, Cp_p, wsS, wsP, wsWc, wsPc);
    k3_emit<<<NB, BLOCK, 0, stream>>>(u, Rp_p, Cp_p, R0_p, ac, wsWc, wsPc, out);
}